// Round 11
// baseline (143.302 us; speedup 1.0000x reference)
//
#include <hip/hip_runtime.h>

// Problem constants (fixed by setup_inputs)
#define NB   16
#define NH   512
#define NW   512
#define RAD  4                   // window 9 -> radius 4
#define BH   4                   // output rows per band
#define NBANDS (NH / BH)         // 128
#define NBLOCKS (NB * NBANDS)    // 2048 blocks (128 threads = 2 waves each)
#define NPART (NBLOCKS * 2)      // per-wave partials: 4096
#define EPSF 1e-5f
#define SBYTES_PER_IMG (NH * NW / 8)          // 32768 bytes (1 bit per pixel)
#define SBYTES_TOTAL   (NB * SBYTES_PER_IMG)  // 512 KB

__device__ __forceinline__ float lncc_val(float Sa, float Sb, float Saa, float Sbb, float Sab) {
    const float inv_n = 1.0f / 81.0f;
    float ma  = Sa * inv_n;
    float mb  = Sb * inv_n;
    // faithful to reference: raw local sum of squares minus mean^2, clipped at 0
    float va  = fmaxf(Saa - ma * ma, 0.0f);
    float vb  = fmaxf(Sbb - mb * mb, 0.0f);
    float cov = Sab - ma * mb;
    return cov * rsqrtf((va + EPSF) * (vb + EPSF));
}

// ---- Pre-pass: argmax(mask, ch) -> 1 bit per pixel, little-endian u32 packing.
__global__ __launch_bounds__(256)
void mask_pre(const float* __restrict__ mask, unsigned* __restrict__ sbits) {
    int tid = blockIdx.x * blockDim.x + threadIdx.x;  // 0..131071
    const size_t hw = (size_t)NH * NW;
    size_t g0 = (size_t)tid * 32;
    int b = (int)(g0 / hw);
    size_t off = g0 - (size_t)b * hw;
    const float* c0 = mask + (size_t)b * 2 * hw + off;
    const float* c1 = c0 + hw;
    unsigned bits = 0;
    #pragma unroll
    for (int j = 0; j < 8; ++j) {
        float4 a  = *reinterpret_cast<const float4*>(c0 + j * 4);
        float4 bb = *reinterpret_cast<const float4*>(c1 + j * 4);
        bits |= (bb.x > a.x ? 1u : 0u) << (j * 4 + 0);
        bits |= (bb.y > a.y ? 1u : 0u) << (j * 4 + 1);
        bits |= (bb.z > a.z ? 1u : 0u) << (j * 4 + 2);
        bits |= (bb.w > a.w ? 1u : 0u) << (j * 4 + 3);
    }
    sbits[tid] = bits;
}

// Add (SGN=+1) or subtract (SGN=-1) one row's products into V. Lane owns 4 cols.
template<int SGN>
__device__ __forceinline__ void accum_row(const float* __restrict__ prow,
                                          const float* __restrict__ trow,
                                          const unsigned char* __restrict__ srow,
                                          int y, int col0,
                                          float (&V)[10][4])
{
    size_t off = (size_t)y * NW + col0;
    float4 pv4 = *reinterpret_cast<const float4*>(prow + off);
    float4 tv4 = *reinterpret_cast<const float4*>(trow + off);
    unsigned byte = srow[y * (NW / 8) + (col0 >> 3)];
    unsigned nib  = (byte >> (col0 & 4)) & 0xFu;   // this lane's 4 bits

    float p[4] = {pv4.x, pv4.y, pv4.z, pv4.w};
    float t[4] = {tv4.x, tv4.y, tv4.z, tv4.w};

    #pragma unroll
    for (int c = 0; c < 4; ++c) {
        float pv = p[c], tv = t[c];
        float s  = (float)((nib >> c) & 1u);
        if (SGN < 0) s = -s;
        float pp = pv * pv, tt = tv * tv, pt = pv * tv;
        if (SGN > 0) {
            V[0][c] += pv; V[1][c] += tv; V[2][c] += pp; V[3][c] += tt; V[4][c] += pt;
        } else {
            V[0][c] -= pv; V[1][c] -= tv; V[2][c] -= pp; V[3][c] -= tt; V[4][c] -= pt;
        }
        V[5][c] = fmaf(s, pv, V[5][c]); V[6][c] = fmaf(s, tv, V[6][c]);
        V[7][c] = fmaf(s, pp, V[7][c]); V[8][c] = fmaf(s, tt, V[8][c]);
        V[9][c] = fmaf(s, pt, V[9][c]);
    }
}

// Horizontal 9-tap for 5 quantities [qbase..qbase+4] -> Hh[5][4].
// Left/right halo from neighbor lanes via shfl; block-interior wave boundary via LDS.
__device__ __forceinline__ void horiz5(const float (&V)[10][4], int qbase,
                                       int lane, int wv,
                                       const float (*xl)[4], const float (*xr)[4],
                                       float (&Hh)[5][4])
{
    #pragma unroll
    for (int qi = 0; qi < 5; ++qi) {
        const int q = qbase + qi;
        float L0 = __shfl_up(V[q][0], 1), L1 = __shfl_up(V[q][1], 1);
        float L2 = __shfl_up(V[q][2], 1), L3 = __shfl_up(V[q][3], 1);
        if (lane == 0) {
            if (wv == 1) { L0 = xl[q][0]; L1 = xl[q][1]; L2 = xl[q][2]; L3 = xl[q][3]; }
            else         { L0 = L1 = L2 = L3 = 0.0f; }   // image left edge
        }
        float R0 = __shfl_down(V[q][0], 1), R1 = __shfl_down(V[q][1], 1);
        float R2 = __shfl_down(V[q][2], 1), R3 = __shfl_down(V[q][3], 1);
        if (lane == 63) {
            if (wv == 0) { R0 = xr[q][0]; R1 = xr[q][1]; R2 = xr[q][2]; R3 = xr[q][3]; }
            else         { R0 = R1 = R2 = R3 = 0.0f; }   // image right edge
        }
        float h = ((L0 + L1) + (L2 + L3))
                + ((V[q][0] + V[q][1]) + (V[q][2] + V[q][3])) + R0;
        Hh[qi][0] = h;
        h += R1 - L0; Hh[qi][1] = h;
        h += R2 - L1; Hh[qi][2] = h;
        h += R3 - L2; Hh[qi][3] = h;
    }
}

__global__ __launch_bounds__(128)
void lncc_main(const float* __restrict__ pred,
               const float* __restrict__ targ,
               const unsigned char* __restrict__ sbits,
               float* __restrict__ part)
{
    // boundary-lane V exchange: [row parity][side: 0 = tid63's V, 1 = tid64's V]
    __shared__ float xchg[2][2][10][4];

    const int tid  = threadIdx.x;       // 0..127 (2 waves)
    const int lane = tid & 63;
    const int wv   = tid >> 6;
    const int col0 = tid * 4;           // lane owns cols [col0, col0+3]
    const int b    = blockIdx.x / NBANDS;
    const int y0   = (blockIdx.x % NBANDS) * BH;

    const size_t hw   = (size_t)NH * NW;
    const float* prow = pred + (size_t)b * hw;
    const float* trow = targ + (size_t)b * hw;
    const unsigned char* srow = sbits + (size_t)b * SBYTES_PER_IMG;

    float V[10][4];
    #pragma unroll
    for (int q = 0; q < 10; ++q)
        #pragma unroll
        for (int c = 0; c < 4; ++c) V[q][c] = 0.0f;

    // warm-up rows [y0-4, y0+3] (rows <0 are zero padding)
    #pragma unroll
    for (int j = -RAD; j < RAD; ++j) {
        int y = y0 + j;
        if (y >= 0) accum_row<1>(prow, trow, srow, y, col0, V);
    }

    float sum_p = 0.0f, sum_n = 0.0f;

    #pragma clang loop unroll(disable)
    for (int r = 0; r < BH; ++r) {
        int y  = y0 + r;
        int ye = y + RAD;
        if (ye < NH) accum_row<1>(prow, trow, srow, ye, col0, V);  // V spans [y-4,y+4]

        // stage interior wave-boundary lanes' V (parity slot -> 1 barrier per row)
        float (*slot)[10][4] = xchg[r & 1];
        if (tid == 63) {
            #pragma unroll
            for (int q = 0; q < 10; ++q)
                #pragma unroll
                for (int c = 0; c < 4; ++c) slot[0][q][c] = V[q][c];
        } else if (tid == 64) {
            #pragma unroll
            for (int q = 0; q < 10; ++q)
                #pragma unroll
                for (int c = 0; c < 4; ++c) slot[1][q][c] = V[q][c];
        }
        __syncthreads();

        // masked quantities first (Mh stays live), then unmasked (Sh transient)
        float Mh[5][4];
        horiz5(V, 5, lane, wv, slot[0], slot[1], Mh);
        #pragma unroll
        for (int c = 0; c < 4; ++c)
            sum_n += lncc_val(Mh[0][c], Mh[1][c], Mh[2][c], Mh[3][c], Mh[4][c]);

        float Sh[5][4];
        horiz5(V, 0, lane, wv, slot[0], slot[1], Sh);
        #pragma unroll
        for (int c = 0; c < 4; ++c)
            sum_p += lncc_val(Sh[0][c] - Mh[0][c], Sh[1][c] - Mh[1][c],
                              Sh[2][c] - Mh[2][c], Sh[3][c] - Mh[3][c],
                              Sh[4][c] - Mh[4][c]);

        // slide: subtract leaving row (re-load; served by L2/L3)
        if (r < BH - 1) {
            int yl = y - RAD;
            if (yl >= 0) accum_row<-1>(prow, trow, srow, yl, col0, V);
        }
    }

    // per-wave reduction; each wave writes its own partial (no extra barrier)
    #pragma unroll
    for (int off = 32; off > 0; off >>= 1) {
        sum_p += __shfl_down(sum_p, off, 64);
        sum_n += __shfl_down(sum_n, off, 64);
    }
    if (lane == 0) {
        int idx = blockIdx.x * 2 + wv;
        part[idx]         = sum_p;
        part[NPART + idx] = sum_n;
    }
}

__global__ void lncc_finalize(const float* __restrict__ part, float* __restrict__ out) {
    __shared__ float w[8];
    int tid = threadIdx.x; // 256 threads
    float sp = 0.0f, sn = 0.0f;
    for (int i = tid; i < NPART; i += 256) {
        sp += part[i];
        sn += part[NPART + i];
    }
    #pragma unroll
    for (int off = 32; off > 0; off >>= 1) {
        sp += __shfl_down(sp, off, 64);
        sn += __shfl_down(sn, off, 64);
    }
    int wave = tid >> 6, lane = tid & 63;
    if (lane == 0) { w[wave] = sp; w[4 + wave] = sn; }
    __syncthreads();
    if (tid == 0) {
        double SP = (double)w[0] + (double)w[1] + (double)w[2] + (double)w[3];
        double SN = (double)w[4] + (double)w[5] + (double)w[6] + (double)w[7];
        const double npix = (double)NB * (double)NH * (double)NW;
        double mp = SP / npix;
        double mn = SN / npix;
        // LOSS_WEIGHT * (BALANCE*(1-mp) - (1-BALANCE)*(1-mn))
        out[0] = (float)(0.2 * (1.0 - mp) - 0.8 * (1.0 - mn));
    }
}

extern "C" void kernel_launch(void* const* d_in, const int* in_sizes, int n_in,
                              void* d_out, int out_size, void* d_ws, size_t ws_size,
                              hipStream_t stream) {
    const float* pred = (const float*)d_in[0];
    const float* targ = (const float*)d_in[1];
    const float* mask = (const float*)d_in[2];
    unsigned* sbits = (unsigned*)d_ws;                       // 512 KB bit field
    float* part = (float*)((char*)d_ws + SBYTES_TOTAL);      // 32 KB partials

    mask_pre<<<dim3(512), dim3(256), 0, stream>>>(mask, sbits);
    lncc_main<<<dim3(NBLOCKS), dim3(128), 0, stream>>>(pred, targ,
                                                       (const unsigned char*)sbits, part);
    lncc_finalize<<<dim3(1), dim3(256), 0, stream>>>(part, (float*)d_out);
}